// Round 10
// baseline (2008.866 us; speedup 1.0000x reference)
//
#include <hip/hip_runtime.h>
#include <hip/hip_fp16.h>

typedef _Float16 half8 __attribute__((ext_vector_type(8)));
typedef float floatx4 __attribute__((ext_vector_type(4)));

// workspace layout
// h exchange: [parity][group4][dim1024][word j=0..3], word j = 8B ulong packing
// batches 4j..4j+3 (f16, batch 4j+r at bits 16r). 2*4*1024*4*8 = 256 KB.
#define HBUF_BYTES (2ull * 4 * 1024 * 4 * 8)
#define CTL_BYTES  (32ull * 1024)           // flags (64x64B) + done[4] at +16KB
#define DONE_OFF_INTS 4096
#define XP_OFF     (HBUF_BYTES + CTL_BYTES)
#define FLAG_STRIDE 16                      // 64 B per member flag

union pack4 { unsigned long long u; _Float16 h[4]; };
union hbits { _Float16 f; unsigned short s; };

__device__ inline half8 cvt8(const float4 a, const float4 b) {
    half8 r;
    r[0] = (_Float16)a.x; r[1] = (_Float16)a.y; r[2] = (_Float16)a.z; r[3] = (_Float16)a.w;
    r[4] = (_Float16)b.x; r[5] = (_Float16)b.y; r[6] = (_Float16)b.z; r[7] = (_Float16)b.w;
    return r;
}

// ---------------------------------------------------------------------------
// xproj role: one 128x128 tile of x_proj = emb[src] @ Wxh^T + b.
// Quarter-first tile order (q = bid2>>9). Publishes via RELEASE fetch_add on
// done[q] (flushes local L2 -> xp visible at MALL for sc0sc1 readers).
// NEVER waits on anything => always drains => no deadlock possible.
// ---------------------------------------------------------------------------
__device__ void xproj_body(char* smem, int bid2,
                           const int* __restrict__ src, const float* __restrict__ emb,
                           const float* __restrict__ Wxh, const float* __restrict__ bxh,
                           _Float16* __restrict__ xp, int* __restrict__ done)
{
    _Float16 (*As)[40] = reinterpret_cast<_Float16(*)[40]>(smem);
    _Float16 (*Bs)[40] = reinterpret_cast<_Float16(*)[40]>(smem + 10240);

    const int tid  = threadIdx.x;
    const int lane = tid & 63;
    const int w    = tid >> 6;
    const int m15  = lane & 15;
    const int quad = lane >> 4;
    const int q    = bid2 >> 9;          // t-quarter (dispatch priority)
    const int jj   = (bid2 >> 3) & 63;   // batch index
    const int bn   = bid2 & 7;
    const int bm   = jj * 4 + q;         // covers b=jj, t in [q*128, q*128+128)
    const int m0   = bm * 128, n0 = bn * 128;
    const int wm   = w & 1, wn = w >> 1;

    const int  srow = tid >> 1;
    const int  scol = (tid & 1) * 16;
    const long arow = (long)src[m0 + srow] * 1024;
    const float* abase = emb + arow + scol;
    const float* bbase = Wxh + (long)(n0 + srow) * 1024 + scol;

    floatx4 zero4 = {0.f, 0.f, 0.f, 0.f};
    floatx4 acc[4][4];
#pragma unroll
    for (int mt = 0; mt < 4; mt++)
#pragma unroll
        for (int nt = 0; nt < 4; nt++) acc[mt][nt] = zero4;

    for (int k0 = 0; k0 < 1024; k0 += 32) {
        __syncthreads();
        float4 a0 = *(const float4*)(abase + k0);
        float4 a1 = *(const float4*)(abase + k0 + 4);
        float4 a2 = *(const float4*)(abase + k0 + 8);
        float4 a3 = *(const float4*)(abase + k0 + 12);
        float4 b0 = *(const float4*)(bbase + k0);
        float4 b1 = *(const float4*)(bbase + k0 + 4);
        float4 b2 = *(const float4*)(bbase + k0 + 8);
        float4 b3 = *(const float4*)(bbase + k0 + 12);
        *(half8*)&As[srow][scol]     = cvt8(a0, a1);
        *(half8*)&As[srow][scol + 8] = cvt8(a2, a3);
        *(half8*)&Bs[srow][scol]     = cvt8(b0, b1);
        *(half8*)&Bs[srow][scol + 8] = cvt8(b2, b3);
        __syncthreads();

        half8 af[4], bf[4];
#pragma unroll
        for (int mt = 0; mt < 4; mt++)
            af[mt] = *(const half8*)&As[wm * 64 + mt * 16 + m15][quad * 8];
#pragma unroll
        for (int nt = 0; nt < 4; nt++)
            bf[nt] = *(const half8*)&Bs[wn * 64 + nt * 16 + m15][quad * 8];
#pragma unroll
        for (int mt = 0; mt < 4; mt++)
#pragma unroll
            for (int nt = 0; nt < 4; nt++)
                acc[mt][nt] = __builtin_amdgcn_mfma_f32_16x16x32_f16(
                    af[mt], bf[nt], acc[mt][nt], 0, 0, 0);
    }

#pragma unroll
    for (int nt = 0; nt < 4; nt++) {
        const int n = n0 + wn * 64 + nt * 16 + m15;
        const float bias = bxh[n];
#pragma unroll
        for (int mt = 0; mt < 4; mt++) {
            const int mrow = m0 + wm * 64 + mt * 16 + quad * 4;
#pragma unroll
            for (int r = 0; r < 4; r++) {
                const int m = mrow + r;
                const int b = m >> 9;
                const int t = m & 511;
                xp[((long)t * 64 + b) * 1024 + n] = (_Float16)(acc[mt][nt][r] + bias);
            }
        }
    }

    __syncthreads();   // drain all waves' xp stores to L2
    if (tid == 0)
        __hip_atomic_fetch_add(done + q * 16, 1, __ATOMIC_RELEASE,
                               __HIP_MEMORY_SCOPE_AGENT);   // L2 writeback + count
}

// quarter gate: ONE poller per block (R5 lesson: never mass-poll one line),
// block-uniform call sites only.
__device__ inline void xp_gate(const int* done, int tn) {
    if ((tn & 127) == 0) {
        if (threadIdx.x == 0) {
            const int* dq = done + (tn >> 7) * 16;
            while (__hip_atomic_load(dq, __ATOMIC_RELAXED,
                                     __HIP_MEMORY_SCOPE_AGENT) < 512)
                __builtin_amdgcn_s_sleep(8);
        }
        __syncthreads();
    }
}

// 4 xp scalars (4 consecutive batches of one dim) via sc0 sc1 MALL-bypass
// loads (stale-clean xp lines may sit in this XCD's L2 — no kernel boundary).
__device__ inline void xp_load4(const _Float16* p, float* xv) {
    unsigned r0, r1, r2, r3;
    asm volatile(
        "global_load_ushort %0, %4, off sc0 sc1\n\t"
        "global_load_ushort %1, %4, off offset:2048 sc0 sc1\n\t"
        "global_load_ushort %2, %5, off sc0 sc1\n\t"
        "global_load_ushort %3, %5, off offset:2048 sc0 sc1\n\t"
        "s_waitcnt vmcnt(0)"
        : "=&v"(r0), "=&v"(r1), "=&v"(r2), "=&v"(r3)
        : "v"(p), "v"(p + 2048)
        : "memory");
    hbits h;
    h.s = (unsigned short)r0; xv[0] = (float)h.f;
    h.s = (unsigned short)r1; xv[1] = (float)h.f;
    h.s = (unsigned short)r2; xv[2] = (float)h.f;
    h.s = (unsigned short)r3; xv[3] = (float)h.f;
}

// ---------------------------------------------------------------------------
// rnn role (R10): 64 blocks = 4 groups x 16 members. Group g owns batches
// [16g,16g+16) — M=16 MFMA tile FULLY live (was 75% zero rows). Member owns
// dims [64m, 64m+64); wave w owns n-tile dims [64m+16w, +16) over FULL K
// => no cross-wave K reduction (cred + one barrier removed from step path).
// Exchange protocol = measured-best R8: producer 8B atomic stores ->
// __syncthreads (vmcnt drain) -> flag; consumer 16-lane flag poll -> sc0sc1
// bulk gather. C-layout reg r = batch 4*quad+r => one perfectly-aligned 8B
// pack per lane, all 256 lanes productive.
// ---------------------------------------------------------------------------
__device__ void rnn_body(char* smem,
                         const float* __restrict__ Whh, const _Float16* __restrict__ xp,
                         unsigned long long* __restrict__ hb, int* __restrict__ flags,
                         const int* __restrict__ done, float* __restrict__ out)
{
    _Float16 (*hstage)[1032] = reinterpret_cast<_Float16(*)[1032]>(smem);

    const int tid    = threadIdx.x;
    const int lane   = tid & 63;
    const int w      = tid >> 6;
    const int m15    = lane & 15;
    const int quad   = lane >> 4;
    const int wg     = blockIdx.x;
    const int g      = wg & 3;
    const int member = wg >> 2;
    const int b0     = g * 16;
    const int dim    = member * 64 + w * 16 + m15;  // lane's output dim
    const int myb    = b0 + quad * 4;               // lane's first batch

    // W_hh B-frags, full K: Wf[kk] = W_hh[dim][kk*32 + quad*8 ..+8] (128 VGPR)
    half8 Wf[32];
#pragma unroll
    for (int kk = 0; kk < 32; kk++) {
        const float* wrow = Whh + (long)dim * 1024 + kk * 32 + quad * 8;
        float4 lo = *(const float4*)(wrow);
        float4 hi = *(const float4*)(wrow + 4);
        Wf[kk] = cvt8(lo, hi);
    }

    float xv[4];
    xp_gate(done, 0);
    xp_load4(xp + (size_t)myb * 1024 + dim, xv);

    int* myflag = flags + (g * 16 + member) * FLAG_STRIDE;
    const int* gflags = flags + g * 16 * FLAG_STRIDE;
    floatx4 zero4 = {0.f, 0.f, 0.f, 0.f};

    for (int t = 0; t < 512; t++) {
        if (t > 0) {
            if (tid < 16) {
                const int* fw = gflags + tid * FLAG_STRIDE;
                while (__hip_atomic_load(fw, __ATOMIC_RELAXED,
                                         __HIP_MEMORY_SCOPE_AGENT) < t)
                    __builtin_amdgcn_s_sleep(1);
            }
            __syncthreads();
        }

        // gather h_t: thread tid owns dims 4tid..4tid+3 = 128 B contiguous,
        // 8x16B sc0sc1 loads (bypass L1+L2, read MALL point of coherence).
        {
            const char* hcu = (const char*)hb
                + ((size_t)(t & 1) * 4 + g) * 32768 + (size_t)tid * 128;
            uint4 v0, v1, v2, v3, v4, v5, v6, v7;
            asm volatile(
                "global_load_dwordx4 %0, %8, off sc0 sc1\n\t"
                "global_load_dwordx4 %1, %8, off offset:16 sc0 sc1\n\t"
                "global_load_dwordx4 %2, %8, off offset:32 sc0 sc1\n\t"
                "global_load_dwordx4 %3, %8, off offset:48 sc0 sc1\n\t"
                "global_load_dwordx4 %4, %8, off offset:64 sc0 sc1\n\t"
                "global_load_dwordx4 %5, %8, off offset:80 sc0 sc1\n\t"
                "global_load_dwordx4 %6, %8, off offset:96 sc0 sc1\n\t"
                "global_load_dwordx4 %7, %8, off offset:112 sc0 sc1\n\t"
                "s_waitcnt vmcnt(0)"
                : "=&v"(v0), "=&v"(v1), "=&v"(v2), "=&v"(v3),
                  "=&v"(v4), "=&v"(v5), "=&v"(v6), "=&v"(v7)
                : "v"(hcu)
                : "memory");

            unsigned long long u[16];
            u[0]  = ((unsigned long long)v0.y << 32) | v0.x;
            u[1]  = ((unsigned long long)v0.w << 32) | v0.z;
            u[2]  = ((unsigned long long)v1.y << 32) | v1.x;
            u[3]  = ((unsigned long long)v1.w << 32) | v1.z;
            u[4]  = ((unsigned long long)v2.y << 32) | v2.x;
            u[5]  = ((unsigned long long)v2.w << 32) | v2.z;
            u[6]  = ((unsigned long long)v3.y << 32) | v3.x;
            u[7]  = ((unsigned long long)v3.w << 32) | v3.z;
            u[8]  = ((unsigned long long)v4.y << 32) | v4.x;
            u[9]  = ((unsigned long long)v4.w << 32) | v4.z;
            u[10] = ((unsigned long long)v5.y << 32) | v5.x;
            u[11] = ((unsigned long long)v5.w << 32) | v5.z;
            u[12] = ((unsigned long long)v6.y << 32) | v6.x;
            u[13] = ((unsigned long long)v6.w << 32) | v6.z;
            u[14] = ((unsigned long long)v7.y << 32) | v7.x;
            u[15] = ((unsigned long long)v7.w << 32) | v7.z;

            // dim e (0..3) word j (0..3) = u[4e+j]; batch b lives in word
            // b>>2 at bits 16*(b&3). Repack to hstage[b][4tid..4tid+3].
#pragma unroll
            for (int b = 0; b < 16; b++) {
                const int j = b >> 2, s = 16 * (b & 3);
                unsigned long long q = 0;
#pragma unroll
                for (int e = 0; e < 4; e++)
                    q |= ((u[4 * e + j] >> s) & 0xffffull) << (16 * e);
                *(unsigned long long*)&hstage[b][tid * 4] = q;
            }
        }
        __syncthreads();

        // MFMA: A[m=batch][k] from LDS, B = Wf, full K — no reduction needed
        floatx4 pacc = zero4;
#pragma unroll
        for (int kk = 0; kk < 32; kk++) {
            half8 a = *(const half8*)&hstage[m15][kk * 32 + quad * 8];
            pacc = __builtin_amdgcn_mfma_f32_16x16x32_f16(a, Wf[kk], pacc, 0, 0, 0);
        }

        // epilogue: reg r = batch myb+r of this lane's dim; one 8B pack/lane
        pack4 p;
#pragma unroll
        for (int r = 0; r < 4; r++) {
            float pre  = pacc[r] + xv[r];
            float e    = __expf(2.0f * pre);
            float hval = 1.0f - 2.0f / (e + 1.0f);   // tanh
            p.h[r] = (_Float16)hval;
            if (t == 511) out[(size_t)(myb + r) * 1024 + dim] = hval;
        }
        __hip_atomic_store(
            hb + (((size_t)((t + 1) & 1) * 4 + g) * 1024 + dim) * 4 + quad,
            p.u, __ATOMIC_RELAXED, __HIP_MEMORY_SCOPE_AGENT);

        // publish: barrier drains every wave's vmcnt(0), then flag store
        __syncthreads();
        if (tid == 0)
            __hip_atomic_store(myflag, t + 1, __ATOMIC_RELAXED,
                               __HIP_MEMORY_SCOPE_AGENT);

        // prefetch xp for t+1 (quarter-gated, block-uniform)
        if (t < 511) {
            xp_gate(done, t + 1);
            xp_load4(xp + ((size_t)(t + 1) * 64 + myb) * 1024 + dim, xv);
        }
    }
}

// ---------------------------------------------------------------------------
// Fused kernel: blocks 0..63 = persistent rnn; 64..2111 = xproj tiles.
// Deadlock-proof at ANY occupancy/dispatch order: 64 rnn blocks < 256 CUs,
// xproj never waits => xproj always drains => all rnn blocks eventually
// co-resident; rnn waits only on xproj output and rnn peers.
// ---------------------------------------------------------------------------
__global__ __launch_bounds__(256, 1) void fused_kernel(
    const int* __restrict__ src, const float* __restrict__ emb,
    const float* __restrict__ Wxh, const float* __restrict__ bxh,
    const float* __restrict__ Whh, _Float16* __restrict__ xp,
    unsigned long long* __restrict__ hb, int* __restrict__ flags,
    int* __restrict__ done, float* __restrict__ out)
{
    __shared__ __align__(16) char smem[33024];
    if (blockIdx.x >= 64) {
        xproj_body(smem, blockIdx.x - 64, src, emb, Wxh, bxh, xp, done);
        return;
    }
    rnn_body(smem, Whh, xp, hb, flags, done, out);
}

extern "C" void kernel_launch(void* const* d_in, const int* in_sizes, int n_in,
                              void* d_out, int out_size, void* d_ws, size_t ws_size,
                              hipStream_t stream) {
    const int*   src = (const int*)d_in[0];
    const float* emb = (const float*)d_in[1];
    const float* Wxh = (const float*)d_in[2];
    const float* bxh = (const float*)d_in[3];
    const float* Whh = (const float*)d_in[4];
    float* out = (float*)d_out;

    char* ws = (char*)d_ws;
    unsigned long long* hb = (unsigned long long*)ws;
    int* flags = (int*)(ws + HBUF_BYTES);
    int* done  = flags + DONE_OFF_INTS;
    _Float16* xp = (_Float16*)(ws + XP_OFF);

    // zero h[0] (f16 zeros are bit-zero), member flags, quarter counters
    (void)hipMemsetAsync(ws, 0, HBUF_BYTES + CTL_BYTES, stream);

    hipLaunchKernelGGL(fused_kernel, dim3(2112), dim3(256), 0, stream,
                       src, emb, Wxh, bxh, Whh, xp, hb, flags, done, out);
}